// Round 13
// baseline (129.419 us; speedup 1.0000x reference)
//
#include <hip/hip_runtime.h>

#define EPSF 1e-6f
#define Bsz 2
#define Tn  512
#define En  1024
#define Hn  256
#define Mtot (Bsz * Tn)          // 1024 rows
typedef unsigned short us_t;
typedef unsigned int   u32_t;

typedef __attribute__((ext_vector_type(8))) __fp16 f16x8;
typedef __attribute__((ext_vector_type(2))) __fp16 h2_t;
typedef __attribute__((ext_vector_type(8))) short  short8;   // raw 16B container
typedef __attribute__((ext_vector_type(4))) float  f32x4;
#define MFMA16(a, b, c) __builtin_amdgcn_mfma_f32_16x16x32_f16((a), (b), (c), 0, 0, 0)

// ---------------------------------------------------------------------------
__device__ __forceinline__ us_t f2h(float f) {
  __fp16 h = (__fp16)f;                       // RNE
  return __builtin_bit_cast(us_t, h);
}
__device__ __forceinline__ float h2f(us_t u) {
  return (float)__builtin_bit_cast(__fp16, u);
}
__device__ __forceinline__ uint2 pack4h(float a, float b, float c, float d) {
  uint2 r;
  r.x = (u32_t)f2h(a) | ((u32_t)f2h(b) << 16);
  r.y = (u32_t)f2h(c) | ((u32_t)f2h(d) << 16);
  return r;
}
__device__ __forceinline__ float block_reduce_sum_256(float v, float* smem) {
  #pragma unroll
  for (int off = 32; off > 0; off >>= 1) v += __shfl_down(v, off, 64);
  const int wave = threadIdx.x >> 6;
  if ((threadIdx.x & 63) == 0) smem[wave] = v;
  __syncthreads();
  float s = smem[0] + smem[1] + smem[2] + smem[3];
  __syncthreads();
  return s;
}

// ---------------------------------------------------------------------------
// K0 tr: transpose+cast w1,w2 -> [256][1024] f16, w3 -> [1024][256] f16.
// 768 blocks.  Block 0 also zeroes the 64 ticket counters.
// ---------------------------------------------------------------------------
__global__ __launch_bounds__(256) void k_tr(
    const float* __restrict__ w1, const float* __restrict__ w2,
    const float* __restrict__ w3,
    us_t* __restrict__ w1t, us_t* __restrict__ w2t, us_t* __restrict__ w3t,
    int* __restrict__ ticket)
{
  const int b = blockIdx.x, t = threadIdx.x;
  if (b == 0 && t < 64) ticket[t] = 0;

  __shared__ float ts[32][33];
  const float* src; us_t* dst; int R, C, tr, tc;
  if (b < 256)      { src = w1; dst = w1t; R = 1024; C = 256;  tr = b >> 3;  tc = b & 7; }
  else if (b < 512) { int k = b - 256; src = w2; dst = w2t; R = 1024; C = 256; tr = k >> 3; tc = k & 7; }
  else              { int k = b - 512; src = w3; dst = w3t; R = 256; C = 1024; tr = k >> 5; tc = k & 31; }

  const int r = t >> 3, c4 = (t & 7) * 4;
  float4 v = *(const float4*)(src + (size_t)(tr * 32 + r) * C + tc * 32 + c4);
  ts[r][c4 + 0] = v.x; ts[r][c4 + 1] = v.y; ts[r][c4 + 2] = v.z; ts[r][c4 + 3] = v.w;
  __syncthreads();
  float o0 = ts[c4 + 0][r], o1 = ts[c4 + 1][r], o2 = ts[c4 + 2][r], o3 = ts[c4 + 3][r];
  *(uint2*)(dst + (size_t)(tc * 32 + r) * R + tr * 32 + c4) = pack4h(o0, o1, o2, o3);
}

// ---------------------------------------------------------------------------
// K1 gemm_fused: block = (mt,nt), nt-major grid (bid = nt*64+mt -> XCD=mt%8).
// Phase A: read 16 x-rows f32 (full K), in-block RMS scale, cast normalized
//          x -> LDS f16 [16][1032] (padded rows).
// Phase B: 4 waves = split-K x4; A-frags from LDS, B-frags batched global.
// Phase C: LDS combine -> Praw[1024][512].
// Phase D: ticket: 16th block per mt does the norm epilogue (bias + row-RMS
//          over each 256-half) -> A row-major, BmT transposed (LDS gather).
// ---------------------------------------------------------------------------
__global__ __launch_bounds__(256, 4) void k_gemm(
    const float* __restrict__ x,
    const us_t* __restrict__ w1t, const us_t* __restrict__ w2t,
    const float* __restrict__ b1, const float* __restrict__ b2,
    float* __restrict__ Praw, int* __restrict__ ticket,
    us_t* __restrict__ A, us_t* __restrict__ BmT)
{
  union SM {
    us_t xs[16][1032];                                  // 33 KB
    struct { float cmb[4][16][32]; us_t ls[16][256]; } ep;
  };
  __shared__ SM sm;
  __shared__ int winf;

  const int blk = blockIdx.x;
  const int mt = blk & 63, nt = blk >> 6;
  const int m0 = mt * 16, n0 = nt * 32;
  const int t = threadIdx.x;

  // ---- Phase A: x rows -> normalized f16 LDS tile ----
  {
    const int r  = t >> 4;            // 0..15 local row
    const int cs = t & 15;            // col-segment
    const float* xr = x + (size_t)(m0 + r) * En;
    float ss = 0.f;
    #pragma unroll
    for (int i = 0; i < 16; ++i) {
      float4 v = *(const float4*)(xr + i * 64 + cs * 4);
      ss += v.x*v.x + v.y*v.y + v.z*v.z + v.w*v.w;
    }
    #pragma unroll
    for (int o = 1; o < 16; o <<= 1) ss += __shfl_xor(ss, o, 64);
    const float sc = rsqrtf(ss * (1.0f / En) + EPSF);
    #pragma unroll
    for (int i = 0; i < 16; ++i) {
      float4 v = *(const float4*)(xr + i * 64 + cs * 4);   // L1-hot re-read
      *(uint2*)&sm.xs[r][i * 64 + cs * 4] =
          pack4h(v.x * sc, v.y * sc, v.z * sc, v.w * sc);
    }
  }
  __syncthreads();

  // ---- Phase B: MFMA (wave wid: k-slice [wid*256, wid*256+256)) ----
  const int wid = t >> 6, lane = t & 63;
  const int lg = lane >> 4, lr = lane & 15;
  const int k0 = wid * 256;

  const us_t* bbase = (n0 < Hn) ? (w1t + (size_t)n0 * En)
                                : (w2t + (size_t)(n0 - Hn) * En);
  const us_t* bp0 = bbase + (size_t)lr * En + k0 + lg * 8;
  const us_t* bp1 = bp0 + (size_t)16 * En;

  f16x8 wf0[8], wf1[8];
  #pragma unroll
  for (int s = 0; s < 8; ++s) wf0[s] = *(const f16x8*)(bp0 + s * 32);
  #pragma unroll
  for (int s = 0; s < 8; ++s) wf1[s] = *(const f16x8*)(bp1 + s * 32);

  f32x4 acc0 = {0.f,0.f,0.f,0.f}, acc1 = acc0;
  #pragma unroll
  for (int s = 0; s < 8; ++s) {
    f16x8 a = *(const f16x8*)&sm.xs[lr][k0 + lg * 8 + s * 32];
    acc0 = MFMA16(a, wf0[s], acc0);
    acc1 = MFMA16(a, wf1[s], acc1);
  }
  __syncthreads();     // xs no longer needed; safe to alias with ep

  // ---- Phase C: combine split-K, write Praw tile ----
  #pragma unroll
  for (int i = 0; i < 4; ++i) {
    sm.ep.cmb[wid][lg * 4 + i][lr]      = acc0[i];
    sm.ep.cmb[wid][lg * 4 + i][16 + lr] = acc1[i];
  }
  __syncthreads();
  #pragma unroll
  for (int e = 0; e < 2; ++e) {
    const int idx = t + e * 256;
    const int row = idx >> 5, col = idx & 31;
    float s = sm.ep.cmb[0][row][col] + sm.ep.cmb[1][row][col]
            + sm.ep.cmb[2][row][col] + sm.ep.cmb[3][row][col];
    Praw[(size_t)(m0 + row) * 512 + n0 + col] = s;
  }

  // ---- Phase D: ticket; 16th arriver norms rows [m0, m0+16) ----
  __threadfence();
  __syncthreads();
  if (t == 0) winf = (atomicAdd(&ticket[mt], 1) == 15);
  __syncthreads();
  if (!winf) return;

  const int r  = t >> 4;           // 0..15 local row
  const int cs = t & 15;           // 16 cols per half per thread
  const float* pr = Praw + (size_t)(m0 + r) * 512;

  // a-half: cols [0,256)
  {
    float v[16]; float ss = 0.f;
    #pragma unroll
    for (int q = 0; q < 4; ++q) {
      float4 d  = *(const float4*)(pr + cs * 16 + q * 4);
      float4 bv = *(const float4*)(b1 + cs * 16 + q * 4);
      v[q*4+0] = d.x + bv.x; v[q*4+1] = d.y + bv.y;
      v[q*4+2] = d.z + bv.z; v[q*4+3] = d.w + bv.w;
    }
    #pragma unroll
    for (int k = 0; k < 16; ++k) ss += v[k] * v[k];
    #pragma unroll
    for (int o = 1; o < 16; o <<= 1) ss += __shfl_xor(ss, o, 64);
    const float sc = rsqrtf(ss * (1.0f / Hn) + EPSF);
    us_t* ao = A + (size_t)(m0 + r) * Hn + cs * 16;
    #pragma unroll
    for (int q = 0; q < 4; ++q)
      ((uint2*)ao)[q] = pack4h(v[q*4]*sc, v[q*4+1]*sc, v[q*4+2]*sc, v[q*4+3]*sc);
  }
  // b-half: cols [256,512) -> LDS -> transpose-gather -> BmT
  {
    float v[16]; float ss = 0.f;
    #pragma unroll
    for (int q = 0; q < 4; ++q) {
      float4 d  = *(const float4*)(pr + Hn + cs * 16 + q * 4);
      float4 bv = *(const float4*)(b2 + cs * 16 + q * 4);
      v[q*4+0] = d.x + bv.x; v[q*4+1] = d.y + bv.y;
      v[q*4+2] = d.z + bv.z; v[q*4+3] = d.w + bv.w;
    }
    #pragma unroll
    for (int k = 0; k < 16; ++k) ss += v[k] * v[k];
    #pragma unroll
    for (int o = 1; o < 16; o <<= 1) ss += __shfl_xor(ss, o, 64);
    const float sc = rsqrtf(ss * (1.0f / Hn) + EPSF);
    #pragma unroll
    for (int q = 0; q < 4; ++q)
      *(uint2*)&sm.ep.ls[r][cs * 16 + q * 4] =
          pack4h(v[q*4]*sc, v[q*4+1]*sc, v[q*4+2]*sc, v[q*4+3]*sc);
  }
  __syncthreads();
  {
    const int h = t;
    us_t col[16];
    #pragma unroll
    for (int j = 0; j < 16; ++j) col[j] = sm.ep.ls[j][h];
    u32_t w[8];
    #pragma unroll
    for (int k = 0; k < 8; ++k)
      w[k] = (u32_t)col[2*k] | ((u32_t)col[2*k+1] << 16);
    const int bb = m0 >> 9, tcol = m0 & 511;
    us_t* bt = BmT + (size_t)bb * Hn * Tn + (size_t)h * Tn + tcol;
    ((uint4*)bt)[0] = make_uint4(w[0], w[1], w[2], w[3]);
    ((uint4*)bt)[1] = make_uint4(w[4], w[5], w[6], w[7]);
  }
}

// ---------------------------------------------------------------------------
// K2 bar: thread h streams its OWN contiguous BmT f16 row; packed f16
// relu-add (v_pk_add/max), per-8j f32 flush.  512 blocks, balanced remap.
// ---------------------------------------------------------------------------
#define JCHB 32
__global__ __launch_bounds__(256) void k_bar(
    const us_t* __restrict__ A, const us_t* __restrict__ BmT,
    us_t* __restrict__ Yb)
{
  const int raw = blockIdx.x;
  const int sel = (raw < 256) ? raw : (511 - raw);
  const int bb  = raw >> 8;
  const int i0  = sel * 2;
  const int h   = threadIdx.x;
  const size_t baseA = (size_t)bb * Tn * Hn;
  const us_t* __restrict__ bt = BmT + (size_t)bb * Hn * Tn + (size_t)h * Tn;

  const __fp16 a0h = __builtin_bit_cast(__fp16, A[baseA + (size_t)i0 * Hn + h]);
  const __fp16 a1h = __builtin_bit_cast(__fp16, A[baseA + (size_t)(i0 + 1) * Hn + h]);
  const float av0 = (float)a0h;
  const float av1 = (float)a1h;
  h2_t z2;  z2[0]  = (__fp16)0.f; z2[1]  = (__fp16)0.f;
  h2_t a02; a02[0] = a0h;         a02[1] = a0h;
  h2_t a12; a12[0] = a1h;         a12[1] = a1h;
  float sum0 = 0.f, sum1 = 0.f;

  const int nfull = i0 & ~(JCHB - 1);
  short8 c0[4], c1[4];

  #define LOADC(dst, jj) { _Pragma("unroll") \
    for (int q = 0; q < 4; ++q) dst[q] = *(const short8*)(bt + (jj) + q * 8); }
  #define PROCP(buf) { _Pragma("unroll") \
    for (int q = 0; q < 4; ++q) { \
      const h2_t* ph = (const h2_t*)&buf[q]; \
      h2_t p0 = z2, p1 = z2; \
      _Pragma("unroll") \
      for (int w2i = 0; w2i < 4; ++w2i) { \
        h2_t bv2 = ph[w2i]; \
        p0 += __builtin_elementwise_max(a02 + bv2, z2); \
        p1 += __builtin_elementwise_max(a12 + bv2, z2); \
      } \
      sum0 += (float)p0[0] + (float)p0[1]; \
      sum1 += (float)p1[0] + (float)p1[1]; } }

  if (nfull > 0) {
    LOADC(c0, 0);
    int j = 0;
    while (true) {
      const bool m1 = (j + JCHB     < nfull);
      const bool m2 = (j + 2 * JCHB < nfull);
      if (m1) LOADC(c1, j + JCHB);
      PROCP(c0);
      j += JCHB;
      if (!m1) break;
      if (m2) LOADC(c0, j + JCHB);
      PROCP(c1);
      j += JCHB;
      if (!m2) break;
    }
  }
  { // predicated scalar f32 tail: j in [nfull, nfull+32), in-bounds (<=511)
    short8 ct[4];
    LOADC(ct, nfull);
    const int lim = i0 - nfull;
    #pragma unroll
    for (int q = 0; q < 4; ++q)
      #pragma unroll
      for (int e = 0; e < 8; ++e) {
        const int jl = q * 8 + e;
        float bv = h2f((us_t)ct[q][e]);
        sum0 += (jl <= lim)     ? fmaxf(av0 + bv, 0.f) : 0.f;
        sum1 += (jl <= lim + 1) ? fmaxf(av1 + bv, 0.f) : 0.f;
      }
  }
  #undef LOADC
  #undef PROCP

  __shared__ float red[4];
  {
    float ss = block_reduce_sum_256(sum0 * sum0, red);
    float c  = (float)(i0 + 1);
    float sc = rsqrtf(ss * (1.0f / Hn) + EPSF * c * c);
    Yb[baseA + (size_t)i0 * Hn + h] = f2h(sum0 * sc);
  }
  {
    float ss = block_reduce_sum_256(sum1 * sum1, red);
    float c  = (float)(i0 + 2);
    float sc = rsqrtf(ss * (1.0f / Hn) + EPSF * c * c);
    Yb[baseA + (size_t)(i0 + 1) * Hn + h] = f2h(sum1 * sc);
  }
}

// ---------------------------------------------------------------------------
// K3 out: out = x + Y @ w3 + b3.  f16 MFMA, wave tile 16x16, K=256, LDS-free.
// Fragment loads fully batched.  1024 blocks x 4 waves.
// ---------------------------------------------------------------------------
__global__ __launch_bounds__(256, 4) void k_out(
    const us_t* __restrict__ Yb, const us_t* __restrict__ w3t,
    const float* __restrict__ x, const float* __restrict__ b3,
    float* __restrict__ out)
{
  const int wid = threadIdx.x >> 6, lane = threadIdx.x & 63;
  const int wg = blockIdx.x * 4 + wid;
  const int nt = wg & 63, mt = wg >> 6;
  const int m0 = mt * 16, n0 = nt * 16;
  const int lg = lane >> 4, lr = lane & 15;

  const us_t* ap = Yb  + (size_t)(m0 + lr) * Hn + lg * 8;
  const us_t* bp = w3t + (size_t)(n0 + lr) * Hn + lg * 8;

  f16x8 a[8], b[8];
  #pragma unroll
  for (int s = 0; s < 8; ++s) a[s] = *(const f16x8*)(ap + s * 32);
  #pragma unroll
  for (int s = 0; s < 8; ++s) b[s] = *(const f16x8*)(bp + s * 32);

  f32x4 acc = {0.f,0.f,0.f,0.f};
  #pragma unroll
  for (int s = 0; s < 8; ++s) acc = MFMA16(a[s], b[s], acc);

  const int row = m0 + lg * 4;
  const int c = n0 + lr;
  const float bv = b3[c];
  #pragma unroll
  for (int i = 0; i < 4; ++i) {
    const size_t o = (size_t)(row + i) * En + c;
    out[o] = x[o] + acc[i] + bv;
  }
}

// ---------------------------------------------------------------------------
extern "C" void kernel_launch(void* const* d_in, const int* in_sizes, int n_in,
                              void* d_out, int out_size, void* d_ws, size_t ws_size,
                              hipStream_t stream) {
  const float* x  = (const float*)d_in[0];
  const float* w1 = (const float*)d_in[1];
  const float* b1 = (const float*)d_in[2];
  const float* w2 = (const float*)d_in[3];
  const float* b2 = (const float*)d_in[4];
  const float* w3 = (const float*)d_in[5];
  const float* b3 = (const float*)d_in[6];
  float* out = (float*)d_out;

  char* q = (char*)d_ws;
  float* Praw = (float*)q;  q += (size_t)Mtot * 512 * 4;   // 2 MB
  us_t* w1t   = (us_t*)q;   q += (size_t)Hn * En * 2;
  us_t* w2t   = (us_t*)q;   q += (size_t)Hn * En * 2;
  us_t* w3t   = (us_t*)q;   q += (size_t)En * Hn * 2;
  us_t* A     = (us_t*)q;   q += (size_t)Mtot * Hn * 2;
  us_t* BmT   = (us_t*)q;   q += (size_t)Mtot * Hn * 2;
  us_t* Yb    = (us_t*)q;   q += (size_t)Mtot * Hn * 2;
  int* ticket = (int*)q;    q += 64 * sizeof(int);

  k_tr  <<<768,  256, 0, stream>>>(w1, w2, w3, w1t, w2t, w3t, ticket);
  k_gemm<<<1024, 256, 0, stream>>>(x, w1t, w2t, b1, b2, Praw, ticket, A, BmT);
  k_bar <<<512,  256, 0, stream>>>(A, BmT, Yb);
  k_out <<<1024, 256, 0, stream>>>(Yb, w3t, x, b3, out);
}

// Round 14
// 51.308 us; speedup vs baseline: 2.5224x; 2.5224x over previous
//
#include <hip/hip_runtime.h>

#define EPSF 1e-6f
#define Bsz 2
#define Tn  512
#define En  1024
#define Hn  256
#define Mtot (Bsz * Tn)          // 1024 rows
typedef unsigned short us_t;
typedef unsigned int   u32_t;

typedef __attribute__((ext_vector_type(8))) __fp16 f16x8;
typedef __attribute__((ext_vector_type(2))) __fp16 h2_t;
typedef __attribute__((ext_vector_type(8))) short  short8;   // raw 16B container
typedef __attribute__((ext_vector_type(4))) float  f32x4;
#define MFMA16(a, b, c) __builtin_amdgcn_mfma_f32_16x16x32_f16((a), (b), (c), 0, 0, 0)

// ---------------------------------------------------------------------------
__device__ __forceinline__ us_t f2h(float f) {
  __fp16 h = (__fp16)f;                       // RNE
  return __builtin_bit_cast(us_t, h);
}
__device__ __forceinline__ float h2f(us_t u) {
  return (float)__builtin_bit_cast(__fp16, u);
}
__device__ __forceinline__ uint2 pack4h(float a, float b, float c, float d) {
  uint2 r;
  r.x = (u32_t)f2h(a) | ((u32_t)f2h(b) << 16);
  r.y = (u32_t)f2h(c) | ((u32_t)f2h(d) << 16);
  return r;
}
// 512-thread block reduce (threads contributing 0 still participate)
__device__ __forceinline__ float block_reduce_sum_512(float v, float* smem) {
  #pragma unroll
  for (int off = 32; off > 0; off >>= 1) v += __shfl_down(v, off, 64);
  const int wave = threadIdx.x >> 6;
  if ((threadIdx.x & 63) == 0) smem[wave] = v;
  __syncthreads();
  float s = smem[0] + smem[1] + smem[2] + smem[3]
          + smem[4] + smem[5] + smem[6] + smem[7];
  __syncthreads();
  return s;
}

// ---------------------------------------------------------------------------
// K0 prep (R11, unchanged): blocks 0..255: cast 4 x-rows + rowscale (XCD
// remap).  blocks 256..1023: transpose+cast one 32x32 tile of w1/w2/w3.
// ---------------------------------------------------------------------------
__global__ __launch_bounds__(256) void k_prep(
    const float* __restrict__ x,
    const float* __restrict__ w1, const float* __restrict__ w2,
    const float* __restrict__ w3,
    us_t* __restrict__ xb, float* __restrict__ rs,
    us_t* __restrict__ w1t, us_t* __restrict__ w2t, us_t* __restrict__ w3t)
{
  const int b = blockIdx.x, t = threadIdx.x;

  if (b < 256) {
    const int wid = t >> 6, lane = t & 63;
    const int q   = b >> 3;
    const int mt  = (b & 7) + 8 * (q & 7);
    const int row = 16 * mt + 4 * (q >> 3) + wid;
    const float4* xp = (const float4*)(x + (size_t)row * En);
    float4 v[4];
    #pragma unroll
    for (int i = 0; i < 4; ++i) v[i] = xp[lane + 64 * i];
    float ss = 0.f;
    #pragma unroll
    for (int i = 0; i < 4; ++i)
      ss += v[i].x*v[i].x + v[i].y*v[i].y + v[i].z*v[i].z + v[i].w*v[i].w;
    #pragma unroll
    for (int off = 32; off > 0; off >>= 1) ss += __shfl_xor(ss, off, 64);
    if (lane == 0) rs[row] = rsqrtf(ss * (1.0f / En) + EPSF);
    uint2* xo = (uint2*)(xb + (size_t)row * En);
    #pragma unroll
    for (int i = 0; i < 4; ++i)
      xo[lane + 64 * i] = pack4h(v[i].x, v[i].y, v[i].z, v[i].w);
    return;
  }

  __shared__ float ts[32][33];
  const int i = b - 256;
  const float* src; us_t* dst; int R, C, tr, tc;
  if (i < 256)      { src = w1; dst = w1t; R = 1024; C = 256;  tr = i >> 3;  tc = i & 7; }
  else if (i < 512) { int k = i - 256; src = w2; dst = w2t; R = 1024; C = 256; tr = k >> 3; tc = k & 7; }
  else              { int k = i - 512; src = w3; dst = w3t; R = 256; C = 1024; tr = k >> 5; tc = k & 31; }

  const int r = t >> 3, c4 = (t & 7) * 4;
  float4 v = *(const float4*)(src + (size_t)(tr * 32 + r) * C + tc * 32 + c4);
  ts[r][c4 + 0] = v.x; ts[r][c4 + 1] = v.y; ts[r][c4 + 2] = v.z; ts[r][c4 + 3] = v.w;
  __syncthreads();
  float o0 = ts[c4 + 0][r], o1 = ts[c4 + 1][r], o2 = ts[c4 + 2][r], o3 = ts[c4 + 3][r];
  *(uint2*)(dst + (size_t)(tc * 32 + r) * R + tr * 32 + c4) = pack4h(o0, o1, o2, o3);
}

// ---------------------------------------------------------------------------
// K1 gemm: 2048 blocks (mt-major: blk = nt*64+mt, XCD = mt%8).  Block = one
// 16x16 output tile, 4 waves = split-K x4 (K=256 each).  LDS combine ->
// Praw[1024][512] f32.  8 blocks/CU target.
// ---------------------------------------------------------------------------
__global__ __launch_bounds__(256, 8) void k_gemm(
    const us_t* __restrict__ xb,
    const us_t* __restrict__ w1t, const us_t* __restrict__ w2t,
    float* __restrict__ Praw)
{
  const int blk = blockIdx.x;
  const int mt = blk & 63, nt = blk >> 6;          // mt 0..63, nt 0..31
  const int m0 = mt * 16, n0 = nt * 16;
  const int wid = threadIdx.x >> 6, lane = threadIdx.x & 63;
  const int lg = lane >> 4, lr = lane & 15;
  const int k0 = wid * 256;

  const us_t* ap = xb + (size_t)(m0 + lr) * En + k0 + lg * 8;
  const us_t* bbase = (n0 < Hn) ? (w1t + (size_t)n0 * En)
                                : (w2t + (size_t)(n0 - Hn) * En);
  const us_t* bp = bbase + (size_t)lr * En + k0 + lg * 8;

  f32x4 acc = {0.f,0.f,0.f,0.f};
  #pragma unroll
  for (int s = 0; s < 8; ++s) {
    f16x8 a = *(const f16x8*)(ap + s * 32);
    f16x8 b = *(const f16x8*)(bp + s * 32);
    acc = MFMA16(a, b, acc);
  }

  __shared__ float cmb[4][16][16];
  #pragma unroll
  for (int i = 0; i < 4; ++i)
    cmb[wid][lg * 4 + i][lr] = acc[i];
  __syncthreads();

  const int row = threadIdx.x >> 4, col = threadIdx.x & 15;
  float s = cmb[0][row][col] + cmb[1][row][col]
          + cmb[2][row][col] + cmb[3][row][col];
  Praw[(size_t)(m0 + row) * 512 + n0 + col] = s;
}

// ---------------------------------------------------------------------------
// K2 norm (R11, unchanged): 512 blocks, wave-per-row, XCD-remapped.
// ---------------------------------------------------------------------------
__global__ __launch_bounds__(256) void k_norm(
    const float* __restrict__ Praw, const float* __restrict__ rs,
    const float* __restrict__ b1, const float* __restrict__ b2,
    us_t* __restrict__ A, us_t* __restrict__ BmT)
{
  const int blk = blockIdx.x, t = threadIdx.x;
  const int wid = t >> 6, lane = t & 63;
  const int h0 = lane * 4;

  if (blk < 256) {                 // ---- a-half ----
    const int mt = blk & 63, sub = blk >> 6;
    const int r  = 16 * mt + 4 * sub + wid;
    float4 d = *(const float4*)(Praw + (size_t)r * 512 + h0);
    const float s0 = rs[r];
    float4 bv = *(const float4*)(b1 + h0);
    float vx = d.x * s0 + bv.x, vy = d.y * s0 + bv.y;
    float vz = d.z * s0 + bv.z, vw = d.w * s0 + bv.w;

    float ss = vx*vx + vy*vy + vz*vz + vw*vw;
    #pragma unroll
    for (int o2 = 32; o2 > 0; o2 >>= 1) ss += __shfl_xor(ss, o2, 64);
    const float sc = rsqrtf(ss * (1.0f / Hn) + EPSF);
    *(uint2*)(A + (size_t)r * Hn + h0) = pack4h(vx*sc, vy*sc, vz*sc, vw*sc);
    return;
  }

  __shared__ us_t ls[4][256];
  const int m  = blk - 256;
  const int mt = m & 63, sub = m >> 6;
  const int r0 = 16 * mt + 4 * sub;
  const int r  = r0 + wid;

  float4 d = *(const float4*)(Praw + (size_t)r * 512 + Hn + h0);
  const float s0 = rs[r];
  float4 bv = *(const float4*)(b2 + h0);
  float vx = d.x * s0 + bv.x, vy = d.y * s0 + bv.y;
  float vz = d.z * s0 + bv.z, vw = d.w * s0 + bv.w;

  float ss = vx*vx + vy*vy + vz*vz + vw*vw;
  #pragma unroll
  for (int o2 = 32; o2 > 0; o2 >>= 1) ss += __shfl_xor(ss, o2, 64);
  const float sc = rsqrtf(ss * (1.0f / Hn) + EPSF);

  *(uint2*)&ls[wid][h0] = pack4h(vx*sc, vy*sc, vz*sc, vw*sc);
  __syncthreads();

  const int h = t;
  u32_t w0  = (u32_t)ls[0][h] | ((u32_t)ls[1][h] << 16);
  u32_t w1v = (u32_t)ls[2][h] | ((u32_t)ls[3][h] << 16);
  const int bb   = r0 >> 9;
  const int tcol = r0 & 511;
  *(uint2*)(BmT + (size_t)bb * Hn * Tn + (size_t)h * Tn + tcol) = make_uint2(w0, w1v);
}

// ---------------------------------------------------------------------------
// K3 bar: 512 threads/block.  Thread (h = t&255, jh = t>>8): jh's alternate
// 32-j chunks of BmT row h (halves each thread's serialized load chain).
// Partials combined in LDS; 512-thread reduce; fused RMSNorm.
// 512 blocks, balanced remap.
// ---------------------------------------------------------------------------
#define JCHB 32
__global__ __launch_bounds__(512) void k_bar(
    const us_t* __restrict__ A, const us_t* __restrict__ BmT,
    us_t* __restrict__ Yb)
{
  const int raw = blockIdx.x;
  const int sel = (raw < 256) ? raw : (511 - raw);
  const int bb  = raw >> 8;
  const int i0  = sel * 2;
  const int t   = threadIdx.x;
  const int h   = t & 255, jh = t >> 8;
  const size_t baseA = (size_t)bb * Tn * Hn;
  const us_t* __restrict__ bt = BmT + (size_t)bb * Hn * Tn + (size_t)h * Tn;

  const __fp16 a0h = __builtin_bit_cast(__fp16, A[baseA + (size_t)i0 * Hn + h]);
  const __fp16 a1h = __builtin_bit_cast(__fp16, A[baseA + (size_t)(i0 + 1) * Hn + h]);
  const float av0 = (float)a0h;
  const float av1 = (float)a1h;
  h2_t z2;  z2[0]  = (__fp16)0.f; z2[1]  = (__fp16)0.f;
  h2_t a02; a02[0] = a0h;         a02[1] = a0h;
  h2_t a12; a12[0] = a1h;         a12[1] = a1h;
  float sum0 = 0.f, sum1 = 0.f;

  const int nch = i0 >> 5;          // number of full 32-j chunks
  short8 c0v[4], c1v[4];

  #define LOADC(dst, jj) { _Pragma("unroll") \
    for (int q = 0; q < 4; ++q) dst[q] = *(const short8*)(bt + (jj) + q * 8); }
  #define PROCP(buf) { _Pragma("unroll") \
    for (int q = 0; q < 4; ++q) { \
      const h2_t* ph = (const h2_t*)&buf[q]; \
      h2_t p0 = z2, p1 = z2; \
      _Pragma("unroll") \
      for (int w2i = 0; w2i < 4; ++w2i) { \
        h2_t bv2 = ph[w2i]; \
        p0 += __builtin_elementwise_max(a02 + bv2, z2); \
        p1 += __builtin_elementwise_max(a12 + bv2, z2); \
      } \
      sum0 += (float)p0[0] + (float)p0[1]; \
      sum1 += (float)p1[0] + (float)p1[1]; } }

  // jh processes chunks ch = jh, jh+2, ... < nch (double-buffered)
  int ch = jh;
  if (ch < nch) {
    LOADC(c0v, ch * JCHB);
    while (true) {
      int nx = ch + 2;
      bool more = (nx < nch);
      if (more) LOADC(c1v, nx * JCHB);
      PROCP(c0v);
      ch = nx;
      if (!more) break;
      nx = ch + 2;
      more = (nx < nch);
      if (more) LOADC(c0v, nx * JCHB);
      PROCP(c1v);
      ch = nx;
      if (!more) break;
    }
  }
  // predicated tail chunk j in [nch*32, i0+2): owner jh == nch&1 (balance)
  if (jh == (nch & 1)) {
    short8 ct[4];
    LOADC(ct, nch * JCHB);
    const int lim = i0 - nch * JCHB;        // 0..30
    #pragma unroll
    for (int q = 0; q < 4; ++q)
      #pragma unroll
      for (int e = 0; e < 8; ++e) {
        const int jl = q * 8 + e;
        float bv = h2f((us_t)ct[q][e]);
        sum0 += (jl <= lim)     ? fmaxf(av0 + bv, 0.f) : 0.f;
        sum1 += (jl <= lim + 1) ? fmaxf(av1 + bv, 0.f) : 0.f;
      }
  }
  #undef LOADC
  #undef PROCP

  __shared__ float part0[2][256], part1[2][256];
  __shared__ float red[8];
  part0[jh][h] = sum0;
  part1[jh][h] = sum1;
  __syncthreads();

  const float tot0 = part0[0][h] + part0[1][h];
  const float tot1 = part1[0][h] + part1[1][h];

  float ss0 = block_reduce_sum_512((jh == 0) ? tot0 * tot0 : 0.f, red);
  float ss1 = block_reduce_sum_512((jh == 0) ? tot1 * tot1 : 0.f, red);

  if (jh == 0) {
    float cA = (float)(i0 + 1);
    float scA = rsqrtf(ss0 * (1.0f / Hn) + EPSF * cA * cA);
    Yb[baseA + (size_t)i0 * Hn + h] = f2h(tot0 * scA);
    float cB = (float)(i0 + 2);
    float scB = rsqrtf(ss1 * (1.0f / Hn) + EPSF * cB * cB);
    Yb[baseA + (size_t)(i0 + 1) * Hn + h] = f2h(tot1 * scB);
  }
}

// ---------------------------------------------------------------------------
// K4 out: out = x + Y @ w3 + b3.  2048 blocks; block = 2 tiles x 2 K-halves
// (wave: tile_local = wid>>1, ks = wid&1, K=128).  LDS combine.
// ---------------------------------------------------------------------------
__global__ __launch_bounds__(256, 8) void k_out(
    const us_t* __restrict__ Yb, const us_t* __restrict__ w3t,
    const float* __restrict__ x, const float* __restrict__ b3,
    float* __restrict__ out)
{
  const int wid = threadIdx.x >> 6, lane = threadIdx.x & 63;
  const int tl = wid >> 1, ks = wid & 1;
  const int wt = blockIdx.x * 2 + tl;          // tile id 0..4095
  const int mt = wt >> 6, nt = wt & 63;
  const int m0 = mt * 16, n0 = nt * 16;
  const int lg = lane >> 4, lr = lane & 15;
  const int k0 = ks * 128;

  const us_t* ap = Yb  + (size_t)(m0 + lr) * Hn + k0 + lg * 8;
  const us_t* bp = w3t + (size_t)(n0 + lr) * Hn + k0 + lg * 8;

  f32x4 acc = {0.f,0.f,0.f,0.f};
  #pragma unroll
  for (int s = 0; s < 4; ++s) {
    f16x8 a = *(const f16x8*)(ap + s * 32);
    f16x8 b = *(const f16x8*)(bp + s * 32);
    acc = MFMA16(a, b, acc);
  }

  __shared__ float cmb[4][16][16];
  #pragma unroll
  for (int i = 0; i < 4; ++i)
    cmb[wid][lg * 4 + i][lr] = acc[i];
  __syncthreads();

  const int row = (threadIdx.x >> 4) & 15, col = threadIdx.x & 15;
  #pragma unroll
  for (int e = 0; e < 2; ++e) {
    if ((threadIdx.x >> 8) == 0) {   // all 256 threads, one pass per tile
      const int wt_e = blockIdx.x * 2 + e;
      const int m0e = (wt_e >> 6) * 16, n0e = (wt_e & 63) * 16;
      float s = cmb[e * 2][row][col] + cmb[e * 2 + 1][row][col];
      const size_t o = (size_t)(m0e + row) * En + n0e + col;
      out[o] = x[o] + s + b3[n0e + col];
    }
  }
}

// ---------------------------------------------------------------------------
extern "C" void kernel_launch(void* const* d_in, const int* in_sizes, int n_in,
                              void* d_out, int out_size, void* d_ws, size_t ws_size,
                              hipStream_t stream) {
  const float* x  = (const float*)d_in[0];
  const float* w1 = (const float*)d_in[1];
  const float* b1 = (const float*)d_in[2];
  const float* w2 = (const float*)d_in[3];
  const float* b2 = (const float*)d_in[4];
  const float* w3 = (const float*)d_in[5];
  const float* b3 = (const float*)d_in[6];
  float* out = (float*)d_out;

  char* q = (char*)d_ws;
  float* Praw = (float*)q;  q += (size_t)Mtot * 512 * 4;   // 2 MB
  us_t* xb    = (us_t*)q;   q += (size_t)Mtot * En * 2;    // 2 MB
  us_t* w1t   = (us_t*)q;   q += (size_t)Hn * En * 2;
  us_t* w2t   = (us_t*)q;   q += (size_t)Hn * En * 2;
  us_t* w3t   = (us_t*)q;   q += (size_t)En * Hn * 2;
  us_t* A     = (us_t*)q;   q += (size_t)Mtot * Hn * 2;
  us_t* BmT   = (us_t*)q;   q += (size_t)Mtot * Hn * 2;
  us_t* Yb    = (us_t*)q;   q += (size_t)Mtot * Hn * 2;
  float* rs   = (float*)q;  q += (size_t)Mtot * 4;

  k_prep<<<1024, 256, 0, stream>>>(x, w1, w2, w3, xb, rs, w1t, w2t, w3t);
  k_gemm<<<2048, 256, 0, stream>>>(xb, w1t, w2t, Praw);
  k_norm<<<512,  256, 0, stream>>>(Praw, rs, b1, b2, A, BmT);
  k_bar <<<512,  512, 0, stream>>>(A, BmT, Yb);
  k_out <<<2048, 256, 0, stream>>>(Yb, w3t, x, b3, out);
}

// Round 15
// 47.059 us; speedup vs baseline: 2.7501x; 1.0903x over previous
//
#include <hip/hip_runtime.h>

#define EPSF 1e-6f
#define Bsz 2
#define Tn  512
#define En  1024
#define Hn  256
#define Mtot (Bsz * Tn)          // 1024 rows
typedef unsigned short us_t;
typedef unsigned int   u32_t;

typedef __attribute__((ext_vector_type(8))) __fp16 f16x8;
typedef __attribute__((ext_vector_type(2))) __fp16 h2_t;
typedef __attribute__((ext_vector_type(8))) short  short8;   // raw 16B container
typedef __attribute__((ext_vector_type(4))) float  f32x4;
#define MFMA16(a, b, c) __builtin_amdgcn_mfma_f32_16x16x32_f16((a), (b), (c), 0, 0, 0)

// ---------------------------------------------------------------------------
__device__ __forceinline__ us_t f2h(float f) {
  __fp16 h = (__fp16)f;                       // RNE
  return __builtin_bit_cast(us_t, h);
}
__device__ __forceinline__ float h2f(us_t u) {
  return (float)__builtin_bit_cast(__fp16, u);
}
__device__ __forceinline__ uint2 pack4h(float a, float b, float c, float d) {
  uint2 r;
  r.x = (u32_t)f2h(a) | ((u32_t)f2h(b) << 16);
  r.y = (u32_t)f2h(c) | ((u32_t)f2h(d) << 16);
  return r;
}
__device__ __forceinline__ float block_reduce_sum_256(float v, float* smem) {
  #pragma unroll
  for (int off = 32; off > 0; off >>= 1) v += __shfl_down(v, off, 64);
  const int wave = threadIdx.x >> 6;
  if ((threadIdx.x & 63) == 0) smem[wave] = v;
  __syncthreads();
  float s = smem[0] + smem[1] + smem[2] + smem[3];
  __syncthreads();
  return s;
}

// ---------------------------------------------------------------------------
// K0 prep (R11): blocks 0..255: cast 4 x-rows + rowscale (XCD remap).
//                blocks 256..1023: transpose+cast one 32x32 tile of w1/w2/w3.
// ---------------------------------------------------------------------------
__global__ __launch_bounds__(256) void k_prep(
    const float* __restrict__ x,
    const float* __restrict__ w1, const float* __restrict__ w2,
    const float* __restrict__ w3,
    us_t* __restrict__ xb, float* __restrict__ rs,
    us_t* __restrict__ w1t, us_t* __restrict__ w2t, us_t* __restrict__ w3t)
{
  const int b = blockIdx.x, t = threadIdx.x;

  if (b < 256) {
    const int wid = t >> 6, lane = t & 63;
    const int q   = b >> 3;
    const int mt  = (b & 7) + 8 * (q & 7);
    const int row = 16 * mt + 4 * (q >> 3) + wid;
    const float4* xp = (const float4*)(x + (size_t)row * En);
    float4 v[4];
    #pragma unroll
    for (int i = 0; i < 4; ++i) v[i] = xp[lane + 64 * i];
    float ss = 0.f;
    #pragma unroll
    for (int i = 0; i < 4; ++i)
      ss += v[i].x*v[i].x + v[i].y*v[i].y + v[i].z*v[i].z + v[i].w*v[i].w;
    #pragma unroll
    for (int off = 32; off > 0; off >>= 1) ss += __shfl_xor(ss, off, 64);
    if (lane == 0) rs[row] = rsqrtf(ss * (1.0f / En) + EPSF);
    uint2* xo = (uint2*)(xb + (size_t)row * En);
    #pragma unroll
    for (int i = 0; i < 4; ++i)
      xo[lane + 64 * i] = pack4h(v[i].x, v[i].y, v[i].z, v[i].w);
    return;
  }

  __shared__ float ts[32][33];
  const int i = b - 256;
  const float* src; us_t* dst; int R, C, tr, tc;
  if (i < 256)      { src = w1; dst = w1t; R = 1024; C = 256;  tr = i >> 3;  tc = i & 7; }
  else if (i < 512) { int k = i - 256; src = w2; dst = w2t; R = 1024; C = 256; tr = k >> 3; tc = k & 7; }
  else              { int k = i - 512; src = w3; dst = w3t; R = 256; C = 1024; tr = k >> 5; tc = k & 31; }

  const int r = t >> 3, c4 = (t & 7) * 4;
  float4 v = *(const float4*)(src + (size_t)(tr * 32 + r) * C + tc * 32 + c4);
  ts[r][c4 + 0] = v.x; ts[r][c4 + 1] = v.y; ts[r][c4 + 2] = v.z; ts[r][c4 + 3] = v.w;
  __syncthreads();
  float o0 = ts[c4 + 0][r], o1 = ts[c4 + 1][r], o2 = ts[c4 + 2][r], o3 = ts[c4 + 3][r];
  *(uint2*)(dst + (size_t)(tc * 32 + r) * R + tr * 32 + c4) = pack4h(o0, o1, o2, o3);
}

// ---------------------------------------------------------------------------
// K1 gemm (R11): block = one 16x32 output tile, 4 waves = in-block split-K x4
// (nt-major grid: XCD = mt%8).  LDS combine -> Praw[1024][512] f32.
// ---------------------------------------------------------------------------
__global__ __launch_bounds__(256, 4) void k_gemm(
    const us_t* __restrict__ xb,
    const us_t* __restrict__ w1t, const us_t* __restrict__ w2t,
    float* __restrict__ Praw)
{
  const int blk = blockIdx.x;
  const int mt = blk & 63, nt = blk >> 6;
  const int m0 = mt * 16, n0 = nt * 32;
  const int wid = threadIdx.x >> 6, lane = threadIdx.x & 63;
  const int lg = lane >> 4, lr = lane & 15;
  const int k0 = wid * 256;

  const us_t* ap = xb + (size_t)(m0 + lr) * En + k0 + lg * 8;
  const us_t* bbase = (n0 < Hn) ? (w1t + (size_t)n0 * En)
                                : (w2t + (size_t)(n0 - Hn) * En);
  const us_t* bp0 = bbase + (size_t)lr * En + k0 + lg * 8;
  const us_t* bp1 = bp0 + (size_t)16 * En;

  f16x8 a[8], wf0[8], wf1[8];
  #pragma unroll
  for (int s = 0; s < 8; ++s) a[s]   = *(const f16x8*)(ap  + s * 32);
  #pragma unroll
  for (int s = 0; s < 8; ++s) wf0[s] = *(const f16x8*)(bp0 + s * 32);
  #pragma unroll
  for (int s = 0; s < 8; ++s) wf1[s] = *(const f16x8*)(bp1 + s * 32);

  f32x4 acc0 = {0.f,0.f,0.f,0.f}, acc1 = acc0;
  #pragma unroll
  for (int s = 0; s < 8; ++s) {
    acc0 = MFMA16(a[s], wf0[s], acc0);
    acc1 = MFMA16(a[s], wf1[s], acc1);
  }

  __shared__ float cmb[4][16][32];
  #pragma unroll
  for (int i = 0; i < 4; ++i) {
    cmb[wid][lg * 4 + i][lr]      = acc0[i];
    cmb[wid][lg * 4 + i][16 + lr] = acc1[i];
  }
  __syncthreads();

  #pragma unroll
  for (int e = 0; e < 2; ++e) {
    const int idx = threadIdx.x + e * 256;
    const int row = idx >> 5, col = idx & 31;
    float s = cmb[0][row][col] + cmb[1][row][col]
            + cmb[2][row][col] + cmb[3][row][col];
    Praw[(size_t)(m0 + row) * 512 + n0 + col] = s;
  }
}

// ---------------------------------------------------------------------------
// K2 norm: b-half ONLY (a-norm moved into k_bar).  256 blocks, wave-per-row,
// XCD-remapped; LDS transpose-gather -> BmT[h][t] f16.
// ---------------------------------------------------------------------------
__global__ __launch_bounds__(256) void k_norm(
    const float* __restrict__ Praw, const float* __restrict__ rs,
    const float* __restrict__ b2, us_t* __restrict__ BmT)
{
  const int blk = blockIdx.x, t = threadIdx.x;
  const int wid = t >> 6, lane = t & 63;
  const int h0 = lane * 4;

  __shared__ us_t ls[4][256];
  const int mt = blk & 63, sub = blk >> 6;
  const int r0 = 16 * mt + 4 * sub;
  const int r  = r0 + wid;

  float4 d = *(const float4*)(Praw + (size_t)r * 512 + Hn + h0);
  const float s0 = rs[r];
  float4 bv = *(const float4*)(b2 + h0);
  float vx = d.x * s0 + bv.x, vy = d.y * s0 + bv.y;
  float vz = d.z * s0 + bv.z, vw = d.w * s0 + bv.w;

  float ss = vx*vx + vy*vy + vz*vz + vw*vw;
  #pragma unroll
  for (int o2 = 32; o2 > 0; o2 >>= 1) ss += __shfl_xor(ss, o2, 64);
  const float sc = rsqrtf(ss * (1.0f / Hn) + EPSF);

  *(uint2*)&ls[wid][h0] = pack4h(vx*sc, vy*sc, vz*sc, vw*sc);
  __syncthreads();

  const int h = t;
  u32_t w0  = (u32_t)ls[0][h] | ((u32_t)ls[1][h] << 16);
  u32_t w1v = (u32_t)ls[2][h] | ((u32_t)ls[3][h] << 16);
  const int bb   = r0 >> 9;
  const int tcol = r0 & 511;
  *(uint2*)(BmT + (size_t)bb * Hn * Tn + (size_t)h * Tn + tcol) = make_uint2(w0, w1v);
}

// ---------------------------------------------------------------------------
// K3 bar: inline a-norm (Praw + rs + b1 -> normalized a in-reg, block
// reduce), then stream own BmT f16 row with packed relu-add, per-8j f32
// flush.  512 blocks, balanced remap.  Fused exact output RMSNorm.
// ---------------------------------------------------------------------------
#define JCHB 32
__global__ __launch_bounds__(256) void k_bar(
    const float* __restrict__ Praw, const float* __restrict__ rs,
    const float* __restrict__ b1,
    const us_t* __restrict__ BmT, us_t* __restrict__ Yb)
{
  __shared__ float red[4];
  const int raw = blockIdx.x;
  const int sel = (raw < 256) ? raw : (511 - raw);
  const int bb  = raw >> 8;
  const int i0  = sel * 2;
  const int h   = threadIdx.x;
  const int rg  = bb * Tn + i0;              // global row of i0
  const size_t baseY = (size_t)bb * Tn * Hn;
  const us_t* __restrict__ bt = BmT + (size_t)bb * Hn * Tn + (size_t)h * Tn;

  // ---- inline a-normalization for rows rg, rg+1 ----
  const float b1h = b1[h];
  float v0 = fmaf(Praw[(size_t)rg * 512 + h],       rs[rg],     b1h);
  float v1 = fmaf(Praw[(size_t)(rg + 1) * 512 + h], rs[rg + 1], b1h);
  float ss0 = block_reduce_sum_256(v0 * v0, red);
  float ss1 = block_reduce_sum_256(v1 * v1, red);
  const float av0 = v0 * rsqrtf(ss0 * (1.0f / Hn) + EPSF);
  const float av1 = v1 * rsqrtf(ss1 * (1.0f / Hn) + EPSF);

  const __fp16 a0h = (__fp16)av0;
  const __fp16 a1h = (__fp16)av1;
  h2_t z2;  z2[0]  = (__fp16)0.f; z2[1]  = (__fp16)0.f;
  h2_t a02; a02[0] = a0h;         a02[1] = a0h;
  h2_t a12; a12[0] = a1h;         a12[1] = a1h;
  float sum0 = 0.f, sum1 = 0.f;

  const int nfull = i0 & ~(JCHB - 1);
  short8 c0[4], c1[4];

  #define LOADC(dst, jj) { _Pragma("unroll") \
    for (int q = 0; q < 4; ++q) dst[q] = *(const short8*)(bt + (jj) + q * 8); }
  #define PROCP(buf) { _Pragma("unroll") \
    for (int q = 0; q < 4; ++q) { \
      const h2_t* ph = (const h2_t*)&buf[q]; \
      h2_t p0 = z2, p1 = z2; \
      _Pragma("unroll") \
      for (int w2i = 0; w2i < 4; ++w2i) { \
        h2_t bv2 = ph[w2i]; \
        p0 += __builtin_elementwise_max(a02 + bv2, z2); \
        p1 += __builtin_elementwise_max(a12 + bv2, z2); \
      } \
      sum0 += (float)p0[0] + (float)p0[1]; \
      sum1 += (float)p1[0] + (float)p1[1]; } }

  if (nfull > 0) {
    LOADC(c0, 0);
    int j = 0;
    while (true) {
      const bool m1 = (j + JCHB     < nfull);
      const bool m2 = (j + 2 * JCHB < nfull);
      if (m1) LOADC(c1, j + JCHB);
      PROCP(c0);
      j += JCHB;
      if (!m1) break;
      if (m2) LOADC(c0, j + JCHB);
      PROCP(c1);
      j += JCHB;
      if (!m2) break;
    }
  }
  { // predicated scalar f32 tail: j in [nfull, nfull+32), in-bounds (<=511)
    short8 ct[4];
    LOADC(ct, nfull);
    const int lim = i0 - nfull;
    #pragma unroll
    for (int q = 0; q < 4; ++q)
      #pragma unroll
      for (int e = 0; e < 8; ++e) {
        const int jl = q * 8 + e;
        float bv = h2f((us_t)ct[q][e]);
        sum0 += (jl <= lim)     ? fmaxf((float)a0h + bv, 0.f) : 0.f;
        sum1 += (jl <= lim + 1) ? fmaxf((float)a1h + bv, 0.f) : 0.f;
      }
  }
  #undef LOADC
  #undef PROCP

  {
    float ss = block_reduce_sum_256(sum0 * sum0, red);
    float c  = (float)(i0 + 1);
    float sc = rsqrtf(ss * (1.0f / Hn) + EPSF * c * c);
    Yb[baseY + (size_t)i0 * Hn + h] = f2h(sum0 * sc);
  }
  {
    float ss = block_reduce_sum_256(sum1 * sum1, red);
    float c  = (float)(i0 + 2);
    float sc = rsqrtf(ss * (1.0f / Hn) + EPSF * c * c);
    Yb[baseY + (size_t)(i0 + 1) * Hn + h] = f2h(sum1 * sc);
  }
}

// ---------------------------------------------------------------------------
// K4 out (R11): out = x + Y @ w3 + b3.  f16 MFMA, wave tile 16x16, K=256,
// LDS-free, batched fragment loads.  1024 blocks x 4 waves.
// ---------------------------------------------------------------------------
__global__ __launch_bounds__(256, 4) void k_out(
    const us_t* __restrict__ Yb, const us_t* __restrict__ w3t,
    const float* __restrict__ x, const float* __restrict__ b3,
    float* __restrict__ out)
{
  const int wid = threadIdx.x >> 6, lane = threadIdx.x & 63;
  const int wg = blockIdx.x * 4 + wid;
  const int nt = wg & 63, mt = wg >> 6;
  const int m0 = mt * 16, n0 = nt * 16;
  const int lg = lane >> 4, lr = lane & 15;

  const us_t* ap = Yb  + (size_t)(m0 + lr) * Hn + lg * 8;
  const us_t* bp = w3t + (size_t)(n0 + lr) * Hn + lg * 8;

  f16x8 a[8], b[8];
  #pragma unroll
  for (int s = 0; s < 8; ++s) a[s] = *(const f16x8*)(ap + s * 32);
  #pragma unroll
  for (int s = 0; s < 8; ++s) b[s] = *(const f16x8*)(bp + s * 32);

  f32x4 acc = {0.f,0.f,0.f,0.f};
  #pragma unroll
  for (int s = 0; s < 8; ++s) acc = MFMA16(a[s], b[s], acc);

  const int row = m0 + lg * 4;
  const int c = n0 + lr;
  const float bv = b3[c];
  #pragma unroll
  for (int i = 0; i < 4; ++i) {
    const size_t o = (size_t)(row + i) * En + c;
    out[o] = x[o] + acc[i] + bv;
  }
}

// ---------------------------------------------------------------------------
extern "C" void kernel_launch(void* const* d_in, const int* in_sizes, int n_in,
                              void* d_out, int out_size, void* d_ws, size_t ws_size,
                              hipStream_t stream) {
  const float* x  = (const float*)d_in[0];
  const float* w1 = (const float*)d_in[1];
  const float* b1 = (const float*)d_in[2];
  const float* w2 = (const float*)d_in[3];
  const float* b2 = (const float*)d_in[4];
  const float* w3 = (const float*)d_in[5];
  const float* b3 = (const float*)d_in[6];
  float* out = (float*)d_out;

  char* q = (char*)d_ws;
  float* Praw = (float*)q;  q += (size_t)Mtot * 512 * 4;   // 2 MB
  us_t* xb    = (us_t*)q;   q += (size_t)Mtot * En * 2;    // 2 MB
  us_t* w1t   = (us_t*)q;   q += (size_t)Hn * En * 2;
  us_t* w2t   = (us_t*)q;   q += (size_t)Hn * En * 2;
  us_t* w3t   = (us_t*)q;   q += (size_t)En * Hn * 2;
  us_t* BmT   = (us_t*)q;   q += (size_t)Mtot * Hn * 2;
  us_t* Yb    = (us_t*)q;   q += (size_t)Mtot * Hn * 2;
  float* rs   = (float*)q;  q += (size_t)Mtot * 4;

  k_prep<<<1024, 256, 0, stream>>>(x, w1, w2, w3, xb, rs, w1t, w2t, w3t);
  k_gemm<<<1024, 256, 0, stream>>>(xb, w1t, w2t, Praw);
  k_norm<<<256,  256, 0, stream>>>(Praw, rs, b2, BmT);
  k_bar <<<512,  256, 0, stream>>>(Praw, rs, b1, BmT, Yb);
  k_out <<<1024, 256, 0, stream>>>(Yb, w3t, x, b3, out);
}